// Round 1
// baseline (329.380 us; speedup 1.0000x reference)
//
#include <hip/hip_runtime.h>
#include <hip/hip_bf16.h>

#define D_MODEL 1024
#define NHEADS  16
#define HDIM    64
#define BATCH   2
#define SEQ     2048
#define MTOT    (BATCH*SEQ)   // 4096

typedef __attribute__((ext_vector_type(8))) short bf16x8;
typedef __attribute__((ext_vector_type(4))) float f32x4;

__device__ __forceinline__ void async_load16(const void* g, void* l) {
    __builtin_amdgcn_global_load_lds(
        (const __attribute__((address_space(1))) void*)g,
        (__attribute__((address_space(3))) void*)l, 16, 0, 0);
}

__device__ __forceinline__ short f2b(float x) {
    __hip_bfloat16 h = __float2bfloat16(x);
    return *reinterpret_cast<short*>(&h);
}

// ---------------- fp32 -> bf16 convert ----------------
__global__ void cvt_kernel(const float* __restrict__ src, short* __restrict__ dst, int n) {
    int i = (blockIdx.x * blockDim.x + threadIdx.x) * 8;
    if (i >= n) return;
    const float4* s4 = (const float4*)(src + i);
    float4 a = s4[0], b = s4[1];
    bf16x8 o;
    o[0]=f2b(a.x); o[1]=f2b(a.y); o[2]=f2b(a.z); o[3]=f2b(a.w);
    o[4]=f2b(b.x); o[5]=f2b(b.y); o[6]=f2b(b.z); o[7]=f2b(b.w);
    *(bf16x8*)(dst + i) = o;
}

// ---------------- shared GEMM core: C[128x128] = A[M,K] * Bt[N,K]^T ----------------
// block 256 threads (4 waves, 2x2), BK=32, global_load_lds width-16 staging.
__device__ __forceinline__ void gemm_core(const short* __restrict__ A,
                                          const short* __restrict__ Bt,
                                          int K, int m0, int n0,
                                          f32x4 (&acc)[4][4]) {
    __shared__ short As[128 * 32];
    __shared__ short Bs[128 * 32];
    const int lane = threadIdx.x & 63;
    const int wid  = threadIdx.x >> 6;
    const int wm   = (wid >> 1) * 64;
    const int wn   = (wid & 1) * 64;
    const int kb   = (lane >> 4) * 8;
    const int rA   = lane >> 2;          // row within 16-row chunk
    const int cA   = (lane & 3) * 8;     // bf16 element col (8 per 16B)

#pragma unroll
    for (int mi = 0; mi < 4; mi++)
#pragma unroll
        for (int ni = 0; ni < 4; ni++)
            acc[mi][ni] = f32x4{0.f, 0.f, 0.f, 0.f};

    for (int k0 = 0; k0 < K; k0 += 32) {
#pragma unroll
        for (int c = 0; c < 2; ++c) {
            int chunk = wid * 2 + c;     // 0..7 (16 rows each)
            const short* ga = A  + (size_t)(m0 + chunk * 16 + rA) * K + k0 + cA;
            async_load16(ga, (char*)As + chunk * 1024);
            const short* gb = Bt + (size_t)(n0 + chunk * 16 + rA) * K + k0 + cA;
            async_load16(gb, (char*)Bs + chunk * 1024);
        }
        __syncthreads();
        bf16x8 af[4], bfr[4];
#pragma unroll
        for (int mi = 0; mi < 4; mi++)
            af[mi] = *(const bf16x8*)&As[(wm + mi * 16 + (lane & 15)) * 32 + kb];
#pragma unroll
        for (int ni = 0; ni < 4; ni++)
            bfr[ni] = *(const bf16x8*)&Bs[(wn + ni * 16 + (lane & 15)) * 32 + kb];
#pragma unroll
        for (int mi = 0; mi < 4; mi++)
#pragma unroll
            for (int ni = 0; ni < 4; ni++)
                acc[mi][ni] = __builtin_amdgcn_mfma_f32_16x16x32_bf16(
                    af[mi], bfr[ni], acc[mi][ni], 0, 0, 0);
        __syncthreads();
    }
}

// ---------------- QKV projection (grid.z selects Q/K/V) ----------------
// Out layout [B, H, S, 64] bf16; Q is pre-scaled by 1/sqrt(64)=0.125 (exact in bf16).
__global__ __launch_bounds__(256) void proj_qkv(
    const short* __restrict__ xq, const short* __restrict__ xk, const short* __restrict__ xv,
    const short* __restrict__ wq, const short* __restrict__ wk, const short* __restrict__ wv,
    const float* __restrict__ bq, const float* __restrict__ bk, const float* __restrict__ bv,
    short* __restrict__ Qo, short* __restrict__ Ko, short* __restrict__ Vo) {
    const int z = blockIdx.z;
    const short* A    = z == 0 ? xq : (z == 1 ? xk : xv);
    const short* Bt   = z == 0 ? wq : (z == 1 ? wk : wv);
    const float* bias = z == 0 ? bq : (z == 1 ? bk : bv);
    short*       Out  = z == 0 ? Qo : (z == 1 ? Ko : Vo);
    const float scale = (z == 0) ? 0.125f : 1.0f;

    const int m0 = blockIdx.y * 128, n0 = blockIdx.x * 128;
    f32x4 acc[4][4];
    gemm_core(A, Bt, D_MODEL, m0, n0, acc);

    const int lane = threadIdx.x & 63;
    const int wid  = threadIdx.x >> 6;
    const int wm = (wid >> 1) * 64, wn = (wid & 1) * 64;
#pragma unroll
    for (int mi = 0; mi < 4; mi++)
#pragma unroll
        for (int ni = 0; ni < 4; ni++)
#pragma unroll
            for (int r = 0; r < 4; r++) {
                int m = m0 + wm + mi * 16 + (lane >> 4) * 4 + r;
                int n = n0 + wn + ni * 16 + (lane & 15);
                float v = (acc[mi][ni][r] + bias[n]) * scale;
                int b = m >> 11, s = m & (SEQ - 1);
                int h = n >> 6, d = n & 63;
                Out[((size_t)(b * NHEADS + h) * SEQ + s) * HDIM + d] = f2b(v);
            }
}

// ---------------- output projection: fp32 out = O @ Wo^T + bo ----------------
__global__ __launch_bounds__(256) void gemm_out(
    const short* __restrict__ O, const short* __restrict__ wo,
    const float* __restrict__ bo, float* __restrict__ out) {
    const int m0 = blockIdx.y * 128, n0 = blockIdx.x * 128;
    f32x4 acc[4][4];
    gemm_core(O, wo, D_MODEL, m0, n0, acc);

    const int lane = threadIdx.x & 63;
    const int wid  = threadIdx.x >> 6;
    const int wm = (wid >> 1) * 64, wn = (wid & 1) * 64;
#pragma unroll
    for (int mi = 0; mi < 4; mi++)
#pragma unroll
        for (int ni = 0; ni < 4; ni++)
#pragma unroll
            for (int r = 0; r < 4; r++) {
                int m = m0 + wm + mi * 16 + (lane >> 4) * 4 + r;
                int n = n0 + wn + ni * 16 + (lane & 15);
                out[(size_t)m * D_MODEL + n] = acc[mi][ni][r] + bo[n];
            }
}

// ---------------- flash attention ----------------
// grid (S/64, B*H); block 256 = 4 waves; each wave owns 16 q rows, full d=64.
// Q pre-scaled. LDS tiles padded to stride 72 (144B rows: 16B aligned, banks spread).
__global__ __launch_bounds__(256) void attn(
    const short* __restrict__ Q, const short* __restrict__ K,
    const short* __restrict__ V, short* __restrict__ O) {
    const int bh = blockIdx.y;          // b*16 + h
    const int b = bh >> 4, h = bh & 15;
    const int q0 = blockIdx.x * 64;
    const int lane = threadIdx.x & 63;
    const int wid  = threadIdx.x >> 6;
    const size_t base = (size_t)bh * SEQ * HDIM;
    const short* Qb = Q + base;
    const short* Kb = K + base;
    const short* Vb = V + base;

    __shared__ short Qs[64 * 72];       // reused as P buffer after Q frags loaded
    __shared__ short Ks[64 * 72];
    __shared__ short Vt[64 * 72];       // Vt[d][k]

    // stage Q tile (64 x 64)
    {
        int r = threadIdx.x >> 2;
        int c = (threadIdx.x & 3) * 16;
        const bf16x8* g = (const bf16x8*)(Qb + (size_t)(q0 + r) * HDIM + c);
        *(bf16x8*)&Qs[r * 72 + c]     = g[0];
        *(bf16x8*)&Qs[r * 72 + c + 8] = g[1];
    }
    __syncthreads();
    const int kb = (lane >> 4) * 8;
    bf16x8 qf[2];
    qf[0] = *(const bf16x8*)&Qs[(wid * 16 + (lane & 15)) * 72 + 0  + kb];
    qf[1] = *(const bf16x8*)&Qs[(wid * 16 + (lane & 15)) * 72 + 32 + kb];

    float m_i[4], l_i[4];
    f32x4 oacc[4];
#pragma unroll
    for (int r = 0; r < 4; r++) { m_i[r] = -1e30f; l_i[r] = 0.f; }
#pragma unroll
    for (int nb = 0; nb < 4; nb++) oacc[nb] = f32x4{0.f, 0.f, 0.f, 0.f};

    short* Ps = Qs + wid * (16 * 72);   // per-wave 16x72 P region

    for (int kt = 0; kt < SEQ / 64; ++kt) {
        __syncthreads();  // prev iter's LDS reads (and initial Q frag reads) done
        // stage K tile and transposed V tile
        {
            int r = threadIdx.x >> 2;
            int c = (threadIdx.x & 3) * 16;
            const bf16x8* gk = (const bf16x8*)(Kb + (size_t)(kt * 64 + r) * HDIM + c);
            *(bf16x8*)&Ks[r * 72 + c]     = gk[0];
            *(bf16x8*)&Ks[r * 72 + c + 8] = gk[1];
            const bf16x8* gv = (const bf16x8*)(Vb + (size_t)(kt * 64 + r) * HDIM + c);
            bf16x8 v0 = gv[0], v1 = gv[1];
#pragma unroll
            for (int j = 0; j < 8; j++) Vt[(c + j) * 72 + r]     = v0[j];
#pragma unroll
            for (int j = 0; j < 8; j++) Vt[(c + 8 + j) * 72 + r] = v1[j];
        }
        __syncthreads();
        // S = Q K^T (pre-scaled)
        f32x4 sa[4];
#pragma unroll
        for (int nb = 0; nb < 4; nb++) {
            bf16x8 k0 = *(const bf16x8*)&Ks[(nb * 16 + (lane & 15)) * 72 + 0  + kb];
            bf16x8 k1 = *(const bf16x8*)&Ks[(nb * 16 + (lane & 15)) * 72 + 32 + kb];
            f32x4 s = f32x4{0.f, 0.f, 0.f, 0.f};
            s = __builtin_amdgcn_mfma_f32_16x16x32_bf16(qf[0], k0, s, 0, 0, 0);
            s = __builtin_amdgcn_mfma_f32_16x16x32_bf16(qf[1], k1, s, 0, 0, 0);
            sa[nb] = s;
        }
        // online softmax per row r = (lane>>4)*4 + r
#pragma unroll
        for (int r = 0; r < 4; r++) {
            float mx = fmaxf(fmaxf(sa[0][r], sa[1][r]), fmaxf(sa[2][r], sa[3][r]));
#pragma unroll
            for (int off = 1; off < 16; off <<= 1) mx = fmaxf(mx, __shfl_xor(mx, off));
            float mnew  = fmaxf(m_i[r], mx);
            float alpha = __expf(m_i[r] - mnew);
            m_i[r] = mnew;
            float rs = 0.f;
#pragma unroll
            for (int nb = 0; nb < 4; nb++) {
                float p = __expf(sa[nb][r] - mnew);
                sa[nb][r] = p;
                rs += p;
            }
#pragma unroll
            for (int off = 1; off < 16; off <<= 1) rs += __shfl_xor(rs, off);
            l_i[r] = l_i[r] * alpha + rs;
#pragma unroll
            for (int nb = 0; nb < 4; nb++) oacc[nb][r] *= alpha;
        }
        // P: C-layout -> LDS -> A-layout
#pragma unroll
        for (int r = 0; r < 4; r++)
#pragma unroll
            for (int nb = 0; nb < 4; nb++)
                Ps[((lane >> 4) * 4 + r) * 72 + nb * 16 + (lane & 15)] = f2b(sa[nb][r]);
        __syncthreads();
        // O += P V
#pragma unroll
        for (int ks = 0; ks < 2; ++ks) {
            bf16x8 pf = *(const bf16x8*)&Ps[(lane & 15) * 72 + ks * 32 + kb];
#pragma unroll
            for (int nb = 0; nb < 4; nb++) {
                bf16x8 vf = *(const bf16x8*)&Vt[(nb * 16 + (lane & 15)) * 72 + ks * 32 + kb];
                oacc[nb] = __builtin_amdgcn_mfma_f32_16x16x32_bf16(pf, vf, oacc[nb], 0, 0, 0);
            }
        }
    }
    // epilogue: O[b, q, h*64 + d] bf16
#pragma unroll
    for (int nb = 0; nb < 4; nb++)
#pragma unroll
        for (int r = 0; r < 4; r++) {
            int q = q0 + wid * 16 + (lane >> 4) * 4 + r;
            int d = h * 64 + nb * 16 + (lane & 15);
            float v = oacc[nb][r] / l_i[r];
            O[(size_t)(b * SEQ + q) * D_MODEL + d] = f2b(v);
        }
}

// ---------------- launcher ----------------
extern "C" void kernel_launch(void* const* d_in, const int* in_sizes, int n_in,
                              void* d_out, int out_size, void* d_ws, size_t ws_size,
                              hipStream_t stream) {
    (void)in_sizes; (void)n_in; (void)out_size; (void)ws_size;
    const float* q_in = (const float*)d_in[0];
    const float* k_in = (const float*)d_in[1];
    const float* v_in = (const float*)d_in[2];
    const float* Wq   = (const float*)d_in[3];
    const float* bq   = (const float*)d_in[4];
    const float* Wk   = (const float*)d_in[5];
    const float* bk   = (const float*)d_in[6];
    const float* Wv   = (const float*)d_in[7];
    const float* bv   = (const float*)d_in[8];
    const float* Wo   = (const float*)d_in[9];
    const float* bo   = (const float*)d_in[10];
    float* out = (float*)d_out;

    constexpr size_t MB = 1ull << 20;
    char* ws = (char*)d_ws;
    short* xq  = (short*)(ws + 0 * MB);    // [4096,1024] bf16, 8MB each
    short* xk  = (short*)(ws + 8 * MB);
    short* xv  = (short*)(ws + 16 * MB);
    short* wqb = (short*)(ws + 24 * MB);   // [1024,1024] bf16, 2MB each
    short* wkb = (short*)(ws + 26 * MB);
    short* wvb = (short*)(ws + 28 * MB);
    short* wob = (short*)(ws + 30 * MB);
    short* Qp  = (short*)(ws + 32 * MB);   // [B,H,S,64] bf16, 8MB each
    short* Kp  = (short*)(ws + 40 * MB);
    short* Vp  = (short*)(ws + 48 * MB);
    short* Op  = (short*)(ws + 56 * MB);   // [B,S,1024] bf16

    const int NX = MTOT * D_MODEL;     // 4,194,304
    const int NW = D_MODEL * D_MODEL;  // 1,048,576

    cvt_kernel<<<NX / 8 / 256, 256, 0, stream>>>(q_in, xq, NX);
    cvt_kernel<<<NX / 8 / 256, 256, 0, stream>>>(k_in, xk, NX);
    cvt_kernel<<<NX / 8 / 256, 256, 0, stream>>>(v_in, xv, NX);
    cvt_kernel<<<NW / 8 / 256, 256, 0, stream>>>(Wq, wqb, NW);
    cvt_kernel<<<NW / 8 / 256, 256, 0, stream>>>(Wk, wkb, NW);
    cvt_kernel<<<NW / 8 / 256, 256, 0, stream>>>(Wv, wvb, NW);
    cvt_kernel<<<NW / 8 / 256, 256, 0, stream>>>(Wo, wob, NW);

    proj_qkv<<<dim3(8, 32, 3), 256, 0, stream>>>(xq, xk, xv, wqb, wkb, wvb,
                                                 bq, bk, bv, Qp, Kp, Vp);
    attn<<<dim3(SEQ / 64, BATCH * NHEADS), 256, 0, stream>>>(Qp, Kp, Vp, Op);
    gemm_out<<<dim3(8, 32), 256, 0, stream>>>(Op, wob, bo, out);
}

// Round 3
// 270.655 us; speedup vs baseline: 1.2170x; 1.2170x over previous
//
#include <hip/hip_runtime.h>
#include <hip/hip_bf16.h>

#define D_MODEL 1024
#define NHEADS  16
#define HDIM    64
#define BATCH   2
#define SEQ     2048
#define MTOT    (BATCH*SEQ)   // 4096

typedef __attribute__((ext_vector_type(8))) short bf16x8;
typedef __attribute__((ext_vector_type(4))) float f32x4;

__device__ __forceinline__ void async_load16(const void* g, void* l) {
    __builtin_amdgcn_global_load_lds(
        (const __attribute__((address_space(1))) void*)g,
        (__attribute__((address_space(3))) void*)l, 16, 0, 0);
}

__device__ __forceinline__ short f2b(float x) {
    __hip_bfloat16 h = __float2bfloat16(x);
    return *reinterpret_cast<short*>(&h);
}
__device__ __forceinline__ unsigned pack2(float lo, float hi) {
    return (unsigned)(unsigned short)f2b(lo) | ((unsigned)(unsigned short)f2b(hi) << 16);
}

// ---------------- fp32 -> bf16 convert (fused: grid.y selects tensor) ----------------
__global__ void cvt3_kernel(const float* __restrict__ s0, const float* __restrict__ s1,
                            const float* __restrict__ s2, short* __restrict__ d0,
                            short* __restrict__ d1, short* __restrict__ d2) {
    const float* src = blockIdx.y == 0 ? s0 : (blockIdx.y == 1 ? s1 : s2);
    short*       dst = blockIdx.y == 0 ? d0 : (blockIdx.y == 1 ? d1 : d2);
    int i = (blockIdx.x * blockDim.x + threadIdx.x) * 8;
    const float4* s4 = (const float4*)(src + i);
    float4 a = s4[0], b = s4[1];
    bf16x8 o;
    o[0]=f2b(a.x); o[1]=f2b(a.y); o[2]=f2b(a.z); o[3]=f2b(a.w);
    o[4]=f2b(b.x); o[5]=f2b(b.y); o[6]=f2b(b.z); o[7]=f2b(b.w);
    *(bf16x8*)(dst + i) = o;
}
__global__ void cvt4_kernel(const float* __restrict__ s0, const float* __restrict__ s1,
                            const float* __restrict__ s2, const float* __restrict__ s3,
                            short* __restrict__ d0, short* __restrict__ d1,
                            short* __restrict__ d2, short* __restrict__ d3) {
    const float* src = blockIdx.y == 0 ? s0 : (blockIdx.y == 1 ? s1 : (blockIdx.y == 2 ? s2 : s3));
    short*       dst = blockIdx.y == 0 ? d0 : (blockIdx.y == 1 ? d1 : (blockIdx.y == 2 ? d2 : d3));
    int i = (blockIdx.x * blockDim.x + threadIdx.x) * 8;
    const float4* s4 = (const float4*)(src + i);
    float4 a = s4[0], b = s4[1];
    bf16x8 o;
    o[0]=f2b(a.x); o[1]=f2b(a.y); o[2]=f2b(a.z); o[3]=f2b(a.w);
    o[4]=f2b(b.x); o[5]=f2b(b.y); o[6]=f2b(b.z); o[7]=f2b(b.w);
    *(bf16x8*)(dst + i) = o;
}

// ---------------- shared GEMM core: C[128x128] = A[M,K] * Bt[N,K]^T ----------------
__device__ __forceinline__ void gemm_core(const short* __restrict__ A,
                                          const short* __restrict__ Bt,
                                          int K, int m0, int n0,
                                          f32x4 (&acc)[4][4]) {
    __shared__ short As[128 * 32];
    __shared__ short Bs[128 * 32];
    const int lane = threadIdx.x & 63;
    const int wid  = threadIdx.x >> 6;
    const int wm   = (wid >> 1) * 64;
    const int wn   = (wid & 1) * 64;
    const int kb   = (lane >> 4) * 8;
    const int rA   = lane >> 2;
    const int cA   = (lane & 3) * 8;

#pragma unroll
    for (int mi = 0; mi < 4; mi++)
#pragma unroll
        for (int ni = 0; ni < 4; ni++)
            acc[mi][ni] = f32x4{0.f, 0.f, 0.f, 0.f};

    for (int k0 = 0; k0 < K; k0 += 32) {
#pragma unroll
        for (int c = 0; c < 2; ++c) {
            int chunk = wid * 2 + c;
            const short* ga = A  + (size_t)(m0 + chunk * 16 + rA) * K + k0 + cA;
            async_load16(ga, (char*)As + chunk * 1024);
            const short* gb = Bt + (size_t)(n0 + chunk * 16 + rA) * K + k0 + cA;
            async_load16(gb, (char*)Bs + chunk * 1024);
        }
        __syncthreads();
        bf16x8 af[4], bfr[4];
#pragma unroll
        for (int mi = 0; mi < 4; mi++)
            af[mi] = *(const bf16x8*)&As[(wm + mi * 16 + (lane & 15)) * 32 + kb];
#pragma unroll
        for (int ni = 0; ni < 4; ni++)
            bfr[ni] = *(const bf16x8*)&Bs[(wn + ni * 16 + (lane & 15)) * 32 + kb];
#pragma unroll
        for (int mi = 0; mi < 4; mi++)
#pragma unroll
            for (int ni = 0; ni < 4; ni++)
                acc[mi][ni] = __builtin_amdgcn_mfma_f32_16x16x32_bf16(
                    af[mi], bfr[ni], acc[mi][ni], 0, 0, 0);
        __syncthreads();
    }
}

// ---------------- QKV projection (grid.z selects Q/K/V) ----------------
__global__ __launch_bounds__(256) void proj_qkv(
    const short* __restrict__ xq, const short* __restrict__ xk, const short* __restrict__ xv,
    const short* __restrict__ wq, const short* __restrict__ wk, const short* __restrict__ wv,
    const float* __restrict__ bq, const float* __restrict__ bk, const float* __restrict__ bv,
    short* __restrict__ Qo, short* __restrict__ Ko, short* __restrict__ Vo) {
    const int z = blockIdx.z;
    const short* A    = z == 0 ? xq : (z == 1 ? xk : xv);
    const short* Bt   = z == 0 ? wq : (z == 1 ? wk : wv);
    const float* bias = z == 0 ? bq : (z == 1 ? bk : bv);
    short*       Out  = z == 0 ? Qo : (z == 1 ? Ko : Vo);
    const float scale = (z == 0) ? 0.125f : 1.0f;

    const int m0 = blockIdx.y * 128, n0 = blockIdx.x * 128;
    f32x4 acc[4][4];
    gemm_core(A, Bt, D_MODEL, m0, n0, acc);

    const int lane = threadIdx.x & 63;
    const int wid  = threadIdx.x >> 6;
    const int wm = (wid >> 1) * 64, wn = (wid & 1) * 64;
#pragma unroll
    for (int mi = 0; mi < 4; mi++)
#pragma unroll
        for (int ni = 0; ni < 4; ni++)
#pragma unroll
            for (int r = 0; r < 4; r++) {
                int m = m0 + wm + mi * 16 + (lane >> 4) * 4 + r;
                int n = n0 + wn + ni * 16 + (lane & 15);
                float v = (acc[mi][ni][r] + bias[n]) * scale;
                int b = m >> 11, s = m & (SEQ - 1);
                int h = n >> 6, d = n & 63;
                Out[((size_t)(b * NHEADS + h) * SEQ + s) * HDIM + d] = f2b(v);
            }
}

// ---------------- output projection ----------------
__global__ __launch_bounds__(256) void gemm_out(
    const short* __restrict__ O, const short* __restrict__ wo,
    const float* __restrict__ bo, float* __restrict__ out) {
    const int m0 = blockIdx.y * 128, n0 = blockIdx.x * 128;
    f32x4 acc[4][4];
    gemm_core(O, wo, D_MODEL, m0, n0, acc);

    const int lane = threadIdx.x & 63;
    const int wid  = threadIdx.x >> 6;
    const int wm = (wid >> 1) * 64, wn = (wid & 1) * 64;
#pragma unroll
    for (int mi = 0; mi < 4; mi++)
#pragma unroll
        for (int ni = 0; ni < 4; ni++)
#pragma unroll
            for (int r = 0; r < 4; r++) {
                int m = m0 + wm + mi * 16 + (lane >> 4) * 4 + r;
                int n = n0 + wn + ni * 16 + (lane & 15);
                out[(size_t)m * D_MODEL + n] = acc[mi][ni][r] + bo[n];
            }
}

// ---------------- V transpose: [BH, S, 64] -> [BH, 64, S] ----------------
__global__ __launch_bounds__(256) void transpose_v(const short* __restrict__ Vp,
                                                   short* __restrict__ Vt) {
    const int bh = blockIdx.y, ts = blockIdx.x;
    __shared__ short T[64][72];
    const int tid = threadIdx.x;
    const int r = tid >> 2, c = (tid & 3) * 16;
    const bf16x8* g = (const bf16x8*)(Vp + ((size_t)bh * SEQ + ts * 64 + r) * HDIM + c);
    *(bf16x8*)&T[r][c]     = g[0];
    *(bf16x8*)&T[r][c + 8] = g[1];   // R2 BUG FIX: second half was never staged
    __syncthreads();
    bf16x8 o0, o1;
#pragma unroll
    for (int j = 0; j < 8; j++) o0[j] = T[c + j][r];
#pragma unroll
    for (int j = 0; j < 8; j++) o1[j] = T[c + 8 + j][r];
    short* dst = Vt + ((size_t)bh * HDIM + r) * SEQ + ts * 64 + c;
    *(bf16x8*)dst = o0;
    *(bf16x8*)(dst + 8) = o1;
}

// ---------------- flash attention, transposed layout ----------------
// grid (S/64, B*H); 4 waves; wave w owns q rows [q0+16w, q0+16w+16).
// S^T = K Q^T so softmax is per-lane (q = lane&15); O^T = V^T P^T via shuffled B-frags.
__global__ __launch_bounds__(256) void attn(
    const short* __restrict__ Q, const short* __restrict__ K,
    const short* __restrict__ Vt, short* __restrict__ O) {
    const int bh = blockIdx.y;
    const int b = bh >> 4, h = bh & 15;
    const int q0 = blockIdx.x * 64;
    const int lane = threadIdx.x & 63;
    const int w = threadIdx.x >> 6;
    const int q = lane & 15, quad = lane >> 4;
    const int lr = lane >> 2;            // staging row within 16
    const int lc = (lane & 3) * 8;       // staging col (shorts)
    const size_t base = (size_t)bh * SEQ * HDIM;
    const short* Qb  = Q + base;
    const short* Kb  = K + base;
    const short* Vtb = Vt + base;        // [64][SEQ]

    // chunked LDS: [c][row][32] shorts, 64B rows -> conflict-free b128 frags,
    // async-load-lds compatible (no padding).
    __shared__ short Qs[2][64][32];
    __shared__ short Ks[2][64][32];
    __shared__ short Vs[2][64][32];

    // stage Q tile once
#pragma unroll
    for (int c = 0; c < 2; ++c)
        async_load16(Qb + (size_t)(q0 + w * 16 + lr) * HDIM + c * 32 + lc, &Qs[c][w * 16][0]);
    __syncthreads();
    bf16x8 qf[2];
    qf[0] = *(const bf16x8*)&Qs[0][w * 16 + q][quad * 8];
    qf[1] = *(const bf16x8*)&Qs[1][w * 16 + q][quad * 8];

    float m_i = -1e30f, l_i = 0.f;
    f32x4 oacc[4];
#pragma unroll
    for (int dt = 0; dt < 4; dt++) oacc[dt] = f32x4{0.f, 0.f, 0.f, 0.f};

    const int s0l = ((quad & 1) << 5) | q;   // shuffle src lane for j=0..3
    const int s1l = s0l + 16;                // j=4..7

    for (int kt = 0; kt < SEQ / 64; ++kt) {
        __syncthreads();
#pragma unroll
        for (int c = 0; c < 2; ++c) {
            async_load16(Kb + (size_t)(kt * 64 + w * 16 + lr) * HDIM + c * 32 + lc,
                         &Ks[c][w * 16][0]);
            async_load16(Vtb + (size_t)(w * 16 + lr) * SEQ + kt * 64 + c * 32 + lc,
                         &Vs[c][w * 16][0]);
        }
        __syncthreads();

        // S^T tiles: rows k = t*16 + quad*4 + r, col q = lane&15 (Q pre-scaled)
        f32x4 st[4];
#pragma unroll
        for (int t = 0; t < 4; t++) {
            bf16x8 kf0 = *(const bf16x8*)&Ks[0][t * 16 + q][quad * 8];
            bf16x8 kf1 = *(const bf16x8*)&Ks[1][t * 16 + q][quad * 8];
            f32x4 s = f32x4{0.f, 0.f, 0.f, 0.f};
            s = __builtin_amdgcn_mfma_f32_16x16x32_bf16(kf0, qf[0], s, 0, 0, 0);
            s = __builtin_amdgcn_mfma_f32_16x16x32_bf16(kf1, qf[1], s, 0, 0, 0);
            st[t] = s;
        }
        // per-lane online softmax (lane owns one q row; k spread over regs+quads)
        float mx = st[0][0];
#pragma unroll
        for (int t = 0; t < 4; t++)
#pragma unroll
            for (int r = 0; r < 4; r++) mx = fmaxf(mx, st[t][r]);
        mx = fmaxf(mx, __shfl_xor(mx, 16));
        mx = fmaxf(mx, __shfl_xor(mx, 32));
        float mnew = fmaxf(m_i, mx);
        float alpha = __expf(m_i - mnew);
        m_i = mnew;
        float rs = 0.f;
#pragma unroll
        for (int t = 0; t < 4; t++)
#pragma unroll
            for (int r = 0; r < 4; r++) {
                float p = __expf(st[t][r] - mnew);
                st[t][r] = p;
                rs += p;
            }
        rs += __shfl_xor(rs, 16);
        rs += __shfl_xor(rs, 32);
        l_i = l_i * alpha + rs;
#pragma unroll
        for (int dt = 0; dt < 4; dt++)
#pragma unroll
            for (int r = 0; r < 4; r++) oacc[dt][r] *= alpha;

        // P B-frags from S^T C-layout via shuffles (no LDS round trip)
        unsigned pk[4][2];
#pragma unroll
        for (int t = 0; t < 4; t++) {
            pk[t][0] = pack2(st[t][0], st[t][1]);
            pk[t][1] = pack2(st[t][2], st[t][3]);
        }
        bf16x8 pb[2];
#pragma unroll
        for (int c = 0; c < 2; ++c) {
            unsigned lo0 = __shfl(pk[2 * c][0], s0l);
            unsigned lo1 = __shfl(pk[2 * c][1], s0l);
            unsigned lo2 = __shfl(pk[2 * c][0], s1l);
            unsigned lo3 = __shfl(pk[2 * c][1], s1l);
            unsigned hi0 = __shfl(pk[2 * c + 1][0], s0l);
            unsigned hi1 = __shfl(pk[2 * c + 1][1], s0l);
            unsigned hi2 = __shfl(pk[2 * c + 1][0], s1l);
            unsigned hi3 = __shfl(pk[2 * c + 1][1], s1l);
            uint4 u;
            u.x = quad < 2 ? lo0 : hi0;
            u.y = quad < 2 ? lo1 : hi1;
            u.z = quad < 2 ? lo2 : hi2;
            u.w = quad < 2 ? lo3 : hi3;
            pb[c] = __builtin_bit_cast(bf16x8, u);
        }
        // O^T += V^T P^T : A = V^T rows d, B = P rows q
#pragma unroll
        for (int dt = 0; dt < 4; dt++) {
            bf16x8 vf0 = *(const bf16x8*)&Vs[0][dt * 16 + q][quad * 8];
            oacc[dt] = __builtin_amdgcn_mfma_f32_16x16x32_bf16(vf0, pb[0], oacc[dt], 0, 0, 0);
            bf16x8 vf1 = *(const bf16x8*)&Vs[1][dt * 16 + q][quad * 8];
            oacc[dt] = __builtin_amdgcn_mfma_f32_16x16x32_bf16(vf1, pb[1], oacc[dt], 0, 0, 0);
        }
    }
    // epilogue: O^T C-layout -> O[b, q, h*64+d]; lane writes 4x 8B runs
    const int qg = q0 + w * 16 + q;
    const float inv = 1.f / l_i;
    short* orow = O + ((size_t)(b * SEQ + qg)) * D_MODEL + h * HDIM;
#pragma unroll
    for (int dt = 0; dt < 4; dt++) {
        short4 s4;
        s4.x = f2b(oacc[dt][0] * inv);
        s4.y = f2b(oacc[dt][1] * inv);
        s4.z = f2b(oacc[dt][2] * inv);
        s4.w = f2b(oacc[dt][3] * inv);
        *(short4*)(orow + dt * 16 + quad * 4) = s4;
    }
}

// ---------------- launcher ----------------
extern "C" void kernel_launch(void* const* d_in, const int* in_sizes, int n_in,
                              void* d_out, int out_size, void* d_ws, size_t ws_size,
                              hipStream_t stream) {
    (void)in_sizes; (void)n_in; (void)out_size; (void)ws_size;
    const float* q_in = (const float*)d_in[0];
    const float* k_in = (const float*)d_in[1];
    const float* v_in = (const float*)d_in[2];
    const float* Wq   = (const float*)d_in[3];
    const float* bq   = (const float*)d_in[4];
    const float* Wk   = (const float*)d_in[5];
    const float* bk   = (const float*)d_in[6];
    const float* Wv   = (const float*)d_in[7];
    const float* bv   = (const float*)d_in[8];
    const float* Wo   = (const float*)d_in[9];
    const float* bo   = (const float*)d_in[10];
    float* out = (float*)d_out;

    constexpr size_t MB = 1ull << 20;
    char* ws = (char*)d_ws;
    short* xq  = (short*)(ws + 0 * MB);    // consumed by proj; reused as VtG after
    short* xk  = (short*)(ws + 8 * MB);
    short* xv  = (short*)(ws + 16 * MB);
    short* wqb = (short*)(ws + 24 * MB);
    short* wkb = (short*)(ws + 26 * MB);
    short* wvb = (short*)(ws + 28 * MB);
    short* wob = (short*)(ws + 30 * MB);
    short* Qp  = (short*)(ws + 32 * MB);   // [BH, S, 64]
    short* Kp  = (short*)(ws + 40 * MB);
    short* Vp  = (short*)(ws + 48 * MB);
    short* Op  = (short*)(ws + 56 * MB);   // [B, S, 1024]
    short* VtG = (short*)(ws + 0 * MB);    // [BH, 64, S] — overwrites xq (safe: proj done)

    cvt3_kernel<<<dim3(MTOT * D_MODEL / 2048, 3), 256, 0, stream>>>(q_in, k_in, v_in, xq, xk, xv);
    cvt4_kernel<<<dim3(D_MODEL * D_MODEL / 2048, 4), 256, 0, stream>>>(Wq, Wk, Wv, Wo,
                                                                       wqb, wkb, wvb, wob);
    proj_qkv<<<dim3(8, 32, 3), 256, 0, stream>>>(xq, xk, xv, wqb, wkb, wvb,
                                                 bq, bk, bv, Qp, Kp, Vp);
    transpose_v<<<dim3(SEQ / 64, BATCH * NHEADS), 256, 0, stream>>>(Vp, VtG);
    attn<<<dim3(SEQ / 64, BATCH * NHEADS), 256, 0, stream>>>(Qp, Kp, VtG, Op);
    gemm_out<<<dim3(8, 32), 256, 0, stream>>>(Op, wob, bo, out);
}